// Round 1
// baseline (958.222 us; speedup 1.0000x reference)
//
#include <hip/hip_runtime.h>

#define NROWS 150000

#define SQK0f 0.05103103630798288f   // 1/sqrt(384)
#define SQK1f 0.04419417382415922f   // 1/sqrt(512)
#define IS3f  0.5773502691896258f    // 1/sqrt(3)
#define IS2f  0.7071067811865476f    // 1/sqrt(2)

typedef __attribute__((ext_vector_type(8))) short short8;
typedef __attribute__((ext_vector_type(4))) float floatx4;

union frag_t { short8 s8; unsigned u[4]; };

// Pack 2 fp32 -> 2 bf16 (RNE) in one instruction. lo -> bits[15:0].
__device__ inline unsigned pk2(float lo, float hi) {
    unsigned r;
    asm("v_cvt_pk_bf16_f32 %0, %1, %2" : "=v"(r) : "v"(lo), "v"(hi));
    return r;
}

// fp32 -> bf16 bits, round-to-nearest-even (prep kernel only; cost irrelevant there)
__device__ inline short f2bf(float f) {
    union { float f; unsigned u; } v;
    v.f = f;
    unsigned u = v.u;
    unsigned r = (u + 0x7FFFu + ((u >> 16) & 1u)) >> 16;
    return (short)(r & 0xFFFFu);
}

// Pack weights into MFMA B-fragment order (UNCHANGED from verified kernel).
// W1 (K=384, N=256) = [w000 (256x256); w110 (128x256)]  -> 12 kb x 16 nt frag blocks
// W2 (K=512, N=128) = [w011 (256x128); w101 (128x128); w111 (128x128)] -> 16 kb x 8 nt
// Fragment block = 64 lanes x 8 bf16; lane l holds B[k0 + (l>>4)*8 + j][n0 + (l&15)].
__global__ void prep_weights(const float* __restrict__ w000,
                             const float* __restrict__ w110,
                             const float* __restrict__ w011,
                             const float* __restrict__ w101,
                             const float* __restrict__ w111,
                             short* __restrict__ W1p,
                             short* __restrict__ W2p)
{
    const int lane = threadIdx.x;   // 64 threads
    const int bid  = blockIdx.x;    // 0..319
    const int m = lane & 15, q = lane >> 4;
    if (bid < 192) {
        const int kb = bid >> 4, nt = bid & 15;
        const int n = nt * 16 + m;
        short8 s;
#pragma unroll
        for (int j = 0; j < 8; ++j) {
            const int k = kb * 32 + q * 8 + j;
            float v = (k < 256) ? w000[k * 256 + n] : w110[(k - 256) * 256 + n];
            s[j] = f2bf(v);
        }
        *(short8*)(W1p + bid * 512 + lane * 8) = s;
    } else {
        const int b2 = bid - 192;
        const int kb = b2 >> 3, nt = b2 & 7;
        const int n = nt * 16 + m;
        short8 s;
#pragma unroll
        for (int j = 0; j < 8; ++j) {
            const int k = kb * 32 + q * 8 + j;
            float v = (k < 256) ? w011[k * 128 + n]
                    : (k < 384) ? w101[(k - 256) * 128 + n]
                                : w111[(k - 384) * 128 + n];
            s[j] = f2bf(v);
        }
        *(short8*)(W2p + b2 * 512 + lane * 8) = s;
    }
}

// ============ Kernel 1: out0 = SQK0*(p000 + p110) + b0 ============
// GEMM1: A1(16x384) @ W1(384x256). acc = 64 VGPRs -> target 4 waves/SIMD.
__global__ __launch_bounds__(256, 4) void k1_out0(
    const float* __restrict__ x, const float* __restrict__ y,
    const float* __restrict__ b0, const short* __restrict__ W1p,
    float* __restrict__ out)
{
    const int lane = threadIdx.x & 63;
    const int wid  = blockIdx.x * 4 + (threadIdx.x >> 6);
    const int R    = wid * 16;
    if (R >= NROWS) return;
    const int m = lane & 15, q = lane >> 4;
    const int row = R + m;

    const float* __restrict__ xr = x + (size_t)row * 640;
    const float4 yv = *(const float4*)(y + (size_t)row * 4);
    const float y0  = yv.x;
    const float ys0 = IS3f * yv.y, ys1 = IS3f * yv.z, ys2 = IS3f * yv.w;

    const short8* __restrict__ W1f = (const short8*)W1p;

    floatx4 acc[16];
#pragma unroll
    for (int nt = 0; nt < 16; ++nt) acc[nt] = (floatx4){0.f, 0.f, 0.f, 0.f};

    // x0 pass: kb 0..7, A = bf16(x0 * y0)
#pragma unroll
    for (int kb = 0; kb < 8; ++kb) {
        const int k0 = kb * 32 + q * 8;
        float4 a0 = *(const float4*)(xr + k0);
        float4 a1 = *(const float4*)(xr + k0 + 4);
        frag_t af;
        af.u[0] = pk2(a0.x * y0, a0.y * y0);
        af.u[1] = pk2(a0.z * y0, a0.w * y0);
        af.u[2] = pk2(a1.x * y0, a1.y * y0);
        af.u[3] = pk2(a1.z * y0, a1.w * y0);
#pragma unroll
        for (int nt = 0; nt < 16; ++nt)
            acc[nt] = __builtin_amdgcn_mfma_f32_16x16x32_bf16(
                af.s8, W1f[(kb * 16 + nt) * 64 + lane], acc[nt], 0, 0, 0);
    }

    // x1 pass: ub 0..3, A = bf16(IS3 * sum_i y1_i * x1_i)  (IS3 folded into ys*)
#pragma unroll
    for (int ub = 0; ub < 4; ++ub) {
        const float* __restrict__ xp = xr + 256 + 3 * (ub * 32 + q * 8);
        float f[24];
#pragma unroll
        for (int c = 0; c < 6; ++c) {
            float4 t = *(const float4*)(xp + 4 * c);
            f[4 * c + 0] = t.x; f[4 * c + 1] = t.y;
            f[4 * c + 2] = t.z; f[4 * c + 3] = t.w;
        }
        float s[8];
#pragma unroll
        for (int j = 0; j < 8; ++j)
            s[j] = f[3 * j] * ys0 + f[3 * j + 1] * ys1 + f[3 * j + 2] * ys2;
        frag_t af;
        af.u[0] = pk2(s[0], s[1]);
        af.u[1] = pk2(s[2], s[3]);
        af.u[2] = pk2(s[4], s[5]);
        af.u[3] = pk2(s[6], s[7]);
#pragma unroll
        for (int nt = 0; nt < 16; ++nt)
            acc[nt] = __builtin_amdgcn_mfma_f32_16x16x32_bf16(
                af.s8, W1f[((8 + ub) * 16 + nt) * 64 + lane], acc[nt], 0, 0, 0);
    }

    // epilogue: lane(m,q) reg r -> D[row_local = q*4 + r][col = m within n-tile]
    float bv[16];
#pragma unroll
    for (int nt = 0; nt < 16; ++nt) bv[nt] = b0[nt * 16 + m];
#pragma unroll
    for (int r = 0; r < 4; ++r) {
        float* __restrict__ orow = out + (size_t)(R + q * 4 + r) * 640;
#pragma unroll
        for (int nt = 0; nt < 16; ++nt)
            orow[nt * 16 + m] = fmaf(SQK0f, acc[nt][r], bv[nt]);
    }
}

// ============ Kernel 2: out1 = SQK1*(p011 + p101 + p111) ============
// GEMM2 per i: A2_i(16x512) @ W2(512x128). acc = 96 VGPRs -> target 3 waves/SIMD.
__global__ __launch_bounds__(256, 3) void k2_out1(
    const float* __restrict__ x, const float* __restrict__ y,
    const short* __restrict__ W2p, float* __restrict__ out)
{
    const int lane = threadIdx.x & 63;
    const int wid  = blockIdx.x * 4 + (threadIdx.x >> 6);
    const int R    = wid * 16;
    if (R >= NROWS) return;
    const int m = lane & 15, q = lane >> 4;
    const int row = R + m;

    const float* __restrict__ xr = x + (size_t)row * 640;
    const float4 yv = *(const float4*)(y + (size_t)row * 4);
    const float y0   = yv.x;
    const float y1c0 = yv.y, y1c1 = yv.z, y1c2 = yv.w;
    const float zc0 = IS2f * y1c0, zc1 = IS2f * y1c1, zc2 = IS2f * y1c2;

    const short8* __restrict__ W2f = (const short8*)W2p;

    floatx4 acc[3][8];
#pragma unroll
    for (int i = 0; i < 3; ++i)
#pragma unroll
        for (int nt = 0; nt < 8; ++nt) acc[i][nt] = (floatx4){0.f, 0.f, 0.f, 0.f};

    // x0 pass: kb 0..7, A_i = bf16(x0 * y1_i)  (p011)
#pragma unroll
    for (int kb = 0; kb < 8; ++kb) {
        const int k0 = kb * 32 + q * 8;
        float4 a0 = *(const float4*)(xr + k0);
        float4 a1 = *(const float4*)(xr + k0 + 4);
        float v[8] = {a0.x, a0.y, a0.z, a0.w, a1.x, a1.y, a1.z, a1.w};
        frag_t af0, af1, af2;
#pragma unroll
        for (int jj = 0; jj < 4; ++jj) {
            af0.u[jj] = pk2(v[2 * jj] * y1c0, v[2 * jj + 1] * y1c0);
            af1.u[jj] = pk2(v[2 * jj] * y1c1, v[2 * jj + 1] * y1c1);
            af2.u[jj] = pk2(v[2 * jj] * y1c2, v[2 * jj + 1] * y1c2);
        }
#pragma unroll
        for (int nt = 0; nt < 8; ++nt) {
            short8 bf = W2f[(kb * 8 + nt) * 64 + lane];
            acc[0][nt] = __builtin_amdgcn_mfma_f32_16x16x32_bf16(af0.s8, bf, acc[0][nt], 0, 0, 0);
            acc[1][nt] = __builtin_amdgcn_mfma_f32_16x16x32_bf16(af1.s8, bf, acc[1][nt], 0, 0, 0);
            acc[2][nt] = __builtin_amdgcn_mfma_f32_16x16x32_bf16(af2.s8, bf, acc[2][nt], 0, 0, 0);
        }
    }

    // x1 pass: ub 0..3 — p101 (A = y0*x1_i) and p111 (A = IS2*cross_i)
#pragma unroll
    for (int ub = 0; ub < 4; ++ub) {
        const float* __restrict__ xp = xr + 256 + 3 * (ub * 32 + q * 8);
        float f[24];
#pragma unroll
        for (int c = 0; c < 6; ++c) {
            float4 t = *(const float4*)(xp + 4 * c);
            f[4 * c + 0] = t.x; f[4 * c + 1] = t.y;
            f[4 * c + 2] = t.z; f[4 * c + 3] = t.w;
        }
        frag_t ap0, ap1, ap2, ac0, ac1, ac2;
#pragma unroll
        for (int jj = 0; jj < 4; ++jj) {
            const int e0 = 6 * jj, e1 = 6 * jj + 3;   // f-base of elements 2jj, 2jj+1
            ap0.u[jj] = pk2(y0 * f[e0 + 0], y0 * f[e1 + 0]);
            ap1.u[jj] = pk2(y0 * f[e0 + 1], y0 * f[e1 + 1]);
            ap2.u[jj] = pk2(y0 * f[e0 + 2], y0 * f[e1 + 2]);
            ac0.u[jj] = pk2(f[e0 + 1] * zc2 - f[e0 + 2] * zc1,
                            f[e1 + 1] * zc2 - f[e1 + 2] * zc1);
            ac1.u[jj] = pk2(f[e0 + 2] * zc0 - f[e0 + 0] * zc2,
                            f[e1 + 2] * zc0 - f[e1 + 0] * zc2);
            ac2.u[jj] = pk2(f[e0 + 0] * zc1 - f[e0 + 1] * zc0,
                            f[e1 + 0] * zc1 - f[e1 + 1] * zc0);
        }
        // p101 part (kb = 8+ub -> w101 rows)
#pragma unroll
        for (int nt = 0; nt < 8; ++nt) {
            short8 bf = W2f[((8 + ub) * 8 + nt) * 64 + lane];
            acc[0][nt] = __builtin_amdgcn_mfma_f32_16x16x32_bf16(ap0.s8, bf, acc[0][nt], 0, 0, 0);
            acc[1][nt] = __builtin_amdgcn_mfma_f32_16x16x32_bf16(ap1.s8, bf, acc[1][nt], 0, 0, 0);
            acc[2][nt] = __builtin_amdgcn_mfma_f32_16x16x32_bf16(ap2.s8, bf, acc[2][nt], 0, 0, 0);
        }
        // cross part (kb = 12+ub -> w111 rows)
#pragma unroll
        for (int nt = 0; nt < 8; ++nt) {
            short8 bf = W2f[((12 + ub) * 8 + nt) * 64 + lane];
            acc[0][nt] = __builtin_amdgcn_mfma_f32_16x16x32_bf16(ac0.s8, bf, acc[0][nt], 0, 0, 0);
            acc[1][nt] = __builtin_amdgcn_mfma_f32_16x16x32_bf16(ac1.s8, bf, acc[1][nt], 0, 0, 0);
            acc[2][nt] = __builtin_amdgcn_mfma_f32_16x16x32_bf16(ac2.s8, bf, acc[2][nt], 0, 0, 0);
        }
    }

    // epilogue: out1 flat index = 256 + 3*w + i, w = nt*16 + m
#pragma unroll
    for (int r = 0; r < 4; ++r) {
        float* __restrict__ orow = out + (size_t)(R + q * 4 + r) * 640 + 256;
#pragma unroll
        for (int nt = 0; nt < 8; ++nt) {
            const int base = 3 * (nt * 16 + m);
            orow[base + 0] = SQK1f * acc[0][nt][r];
            orow[base + 1] = SQK1f * acc[1][nt][r];
            orow[base + 2] = SQK1f * acc[2][nt][r];
        }
    }
}

extern "C" void kernel_launch(void* const* d_in, const int* in_sizes, int n_in,
                              void* d_out, int out_size, void* d_ws, size_t ws_size,
                              hipStream_t stream)
{
    const float* x    = (const float*)d_in[0];
    const float* y    = (const float*)d_in[1];
    const float* w000 = (const float*)d_in[2];
    const float* w110 = (const float*)d_in[3];
    const float* w011 = (const float*)d_in[4];
    const float* w101 = (const float*)d_in[5];
    const float* w111 = (const float*)d_in[6];
    const float* b0   = (const float*)d_in[7];
    float* out = (float*)d_out;

    short* W1p = (short*)d_ws;              // 192 frag blocks * 512 shorts
    short* W2p = (short*)d_ws + 98304;      // 128 frag blocks * 512 shorts

    prep_weights<<<320, 64, 0, stream>>>(w000, w110, w011, w101, w111, W1p, W2p);

    const int waves  = (NROWS + 15) / 16;   // 9375
    const int blocks = (waves + 3) / 4;     // 2344 (last wave early-exits)
    k1_out0<<<blocks, 256, 0, stream>>>(x, y, b0, W1p, out);
    k2_out1<<<blocks, 256, 0, stream>>>(x, y, W2p, out);
}